// Round 1
// baseline (275.164 us; speedup 1.0000x reference)
//
#include <hip/hip_runtime.h>

// ---------------------------------------------------------------------------
// QKVAttention: out[b,c,t] = softmax_s( (q/8)·k + mask )[t,s] · v[c,s]
// N=32, CH=64, T=2048, S_enc=77, S_tot=2125 (pad 2176 = 34 tiles of 64)
// v7: latency-bound fix. s-split x2 inside the block (512 thr: waves 0-3 do
//     s-tiles 0..16, waves 4-7 do 17..33; fixed-max softmax => partials add
//     exactly). V read direct from global (L2/L3-resident) instead of LDS.
//     LDS 73728/block -> 2 blocks/CU -> 16 waves/CU (2x occupancy).
// ---------------------------------------------------------------------------

typedef __attribute__((ext_vector_type(8))) __bf16 bf16x8;
typedef __attribute__((ext_vector_type(8))) unsigned short u16x8;
typedef __attribute__((ext_vector_type(4))) float f32x4;
typedef float f32x4a __attribute__((ext_vector_type(4))) __attribute__((aligned(4)));
typedef __attribute__((ext_vector_type(4))) unsigned u32x4;
typedef __attribute__((ext_vector_type(2))) unsigned u32x2;

#define L2E  1.44269504089f
#define NEGM (-23.0830936f)   /* -16 * log2(e): fixed softmax max */

static __device__ __forceinline__ unsigned short f2bf(float f) {
    unsigned u = __builtin_bit_cast(unsigned, f);
    u += 0x7fffu + ((u >> 16) & 1u);   // round-to-nearest-even
    return (unsigned short)(u >> 16);
}

static __device__ __forceinline__ unsigned pack_bf16(float a, float b) {
#if __has_builtin(__builtin_amdgcn_cvt_pk_bf16_f32)
    typedef __bf16 bf16x2_t __attribute__((ext_vector_type(2)));
    bf16x2_t r = __builtin_amdgcn_cvt_pk_bf16_f32(a, b);
    unsigned u; __builtin_memcpy(&u, &r, 4);
    return u;
#else
    unsigned ua = __builtin_bit_cast(unsigned, a);
    unsigned ub = __builtin_bit_cast(unsigned, b);
    ua += 0x7fffu + ((ua >> 16) & 1u);
    ub += 0x7fffu + ((ub >> 16) & 1u);
    return __builtin_amdgcn_perm(ub, ua, 0x07060302u);
#endif
}

// ---------------------------------------------------------------------------
// Merged prep (unchanged, verified). blocks: [0,1024) K-self transpose,
// [1024,1088) K-enc transpose, [1088,3136) V rows.
// K_ws[n][s][c] (2176 rows; pad rows poison — masked in flash),
// V_ws[n][c][s] (zero-padded to 2176).
// ---------------------------------------------------------------------------
__global__ __launch_bounds__(256) void prep_all(const float* __restrict__ qkv,
                                                const float* __restrict__ ekv,
                                                unsigned short* __restrict__ kws,
                                                unsigned short* __restrict__ vws) {
    int b = blockIdx.x;
    int tid = threadIdx.x;

    if (b >= 1088) {                    // ---- V mode: one (n,c) row
        int bb = b - 1088;
        int n = bb >> 6, c = bb & 63;
        const float* v  = qkv + (size_t)n * 192 * 2048 + (size_t)(128 + c) * 2048;
        const float* ev = ekv + (size_t)n * 128 * 77 + (size_t)(64 + c) * 77;
        unsigned short* dst = vws + ((size_t)n * 64 + c) * 2176;
        for (int u = tid; u < 544; u += 256) {
            int s = u << 2;
            float f[4];
            if (u >= 20 && u <= 530) {           // pure self-V region
                f32x4a x = *(const f32x4a*)(v + s - 77);
                f[0] = x.x; f[1] = x.y; f[2] = x.z; f[3] = x.w;
            } else {
                #pragma unroll
                for (int k = 0; k < 4; ++k) {
                    int sk = s + k;
                    f[k] = (sk < 77) ? ev[sk] : ((sk < 2125) ? v[sk - 77] : 0.f);
                }
            }
            u32x2 pk; pk.x = pack_bf16(f[0], f[1]); pk.y = pack_bf16(f[2], f[3]);
            *(u32x2*)(dst + s) = pk;
        }
        return;
    }

    // ---- K transpose modes (self / enc): [c][t] -> [t][c]
    __shared__ float tile[64][65];
    int mode, n, t0;
    if (b < 1024) { mode = 1; n = b >> 5;          t0 = (b & 31) << 6; }
    else          { mode = 2; n = (b - 1024) >> 1; t0 = ((b - 1024) & 1) << 6; }

    const float* src;
    size_t srow;
    int tmax = 64;
    if (mode == 1) { src = qkv + (size_t)n * 192 * 2048 + (size_t)64 * 2048 + t0; srow = 2048; }
    else           { src = ekv + (size_t)n * 128 * 77 + t0; srow = 77;
                     tmax = 77 - t0; if (tmax > 64) tmax = 64; }

    #pragma unroll
    for (int i = 0; i < 4; ++i) {
        int idx = tid + (i << 8);
        int c  = idx >> 4;
        int t4 = (idx & 15) << 2;
        const float* p = src + (size_t)c * srow + t4;
        float v0, v1, v2, v3;
        if (mode == 1) {
            f32x4 v = *(const f32x4*)p;
            v0 = v.x; v1 = v.y; v2 = v.z; v3 = v.w;
        } else {
            v0 = (t4 + 0 < tmax) ? p[0] : 0.f;
            v1 = (t4 + 1 < tmax) ? p[1] : 0.f;
            v2 = (t4 + 2 < tmax) ? p[2] : 0.f;
            v3 = (t4 + 3 < tmax) ? p[3] : 0.f;
        }
        tile[t4 + 0][c] = v0;
        tile[t4 + 1][c] = v1;
        tile[t4 + 2][c] = v2;
        tile[t4 + 3][c] = v3;
    }
    __syncthreads();
    #pragma unroll
    for (int i = 0; i < 4; ++i) {       // 1024 b64 units (row, 4c)
        int idx = tid + (i << 8);
        int row = idx >> 4;
        int c4  = (idx & 15) << 2;
        if (mode == 2 && row >= tmax) continue;
        u32x2 pk;
        pk.x = pack_bf16(tile[row][c4 + 0], tile[row][c4 + 1]);
        pk.y = pack_bf16(tile[row][c4 + 2], tile[row][c4 + 3]);
        unsigned short* dst;
        if (mode == 1) dst = kws + ((size_t)n * 2176 + 77 + t0 + row) * 64;
        else           dst = kws + ((size_t)n * 2176 + t0 + row) * 64;
        *(u32x2*)(dst + c4) = pk;
    }
}

// ---------------------------------------------------------------------------
// Flash attention v7. 512 threads = 8 waves: wave = 4*h2 + wv.
//   h2 = s-half (0: tiles 0..16, 1: tiles 17..33), wv = t-position.
//   t-tile = 128 (4 wv x 32 t-cols, two 16-col halves). 17 s-tiles per wave.
// S^T = K·Q^T, O^T = V·P^T, mfma_f32_16x16x32_bf16.
// K: register-relay + per-half double-buffered LDS, ONE barrier per tile.
// V: direct global fragment reads (vws is L2/L3-resident; 64B-contig rows).
// P: per-wave LDS scratch (no barrier).
// Fixed softmax max => cross-half (O, lsum) combine is exact addition,
// done once in LDS at the end (reusing the K region).
// Hazard (as v6): reads of k buf[x] (iter k) precede barrier(k+1); writes of
// buf[x] (iter k+2) follow it. LDS rows padded +8 shorts (144B stride).
// Layouts (verified R1/v3/v4/v5): A[m=lane&15][k=quad*8+j],
// B[k=quad*8+j][n=lane&15], C/D: col=lane&15, row=quad*4+reg.
// ---------------------------------------------------------------------------
__global__ __launch_bounds__(512, 4) void flash_attn(
        const float* __restrict__ qkv,
        const unsigned short* __restrict__ kws,
        const unsigned short* __restrict__ vws,
        const float* __restrict__ mask,
        float* __restrict__ out) {
    __shared__ alignas(16) unsigned short k_lds[2][2][64 * 72]; // [half][buf] 36864B
    __shared__ alignas(16) unsigned short p_lds[8][32 * 72];    // 36864B per-wave P[t][s]

    const int n    = blockIdx.y;
    const int t0   = blockIdx.x << 7;
    const int tid  = threadIdx.x;
    const int wave = tid >> 6;
    const int h2   = wave >> 2;                // s-half
    const int wv   = wave & 3;                 // t-position
    const int lane = tid & 63;
    const int q    = lane >> 4;
    const int l16  = lane & 15;
    const int tc0  = t0 + (wv << 5) + l16;     // half 0 column
    const int tc1  = tc0 + 16;                 // half 1 column
    const int sb   = h2 * 1088;                // 17 tiles * 64

    // ---- Q B-fragments for both halves, direct from fp32 qkv[n][c][t]
    bf16x8 qf[2][2];
    #pragma unroll
    for (int h = 0; h < 2; ++h) {
        const float* qsrc = qkv + (size_t)n * 192 * 2048 + (h ? tc1 : tc0);
        u16x8 a0, a1;
        #pragma unroll
        for (int j = 0; j < 8; ++j) {
            a0[j] = f2bf(qsrc[(size_t)((q << 3) + j) * 2048] * 0.125f);
            a1[j] = f2bf(qsrc[(size_t)(32 + (q << 3) + j) * 2048] * 0.125f);
        }
        qf[h][0] = __builtin_bit_cast(bf16x8, a0);
        qf[h][1] = __builtin_bit_cast(bf16x8, a1);
    }

    const unsigned short* kg = kws + (size_t)n * 2176 * 64;
    const unsigned short* vg = vws + (size_t)n * 64 * 2176;
    const float* mrow0 = mask + (size_t)tc0 * 2125;
    const float* mrow1 = mask + (size_t)tc1 * 2125;
    unsigned short* const pw0 = p_lds[wave] + (size_t)l16 * 72;
    unsigned short* const pw1 = p_lds[wave] + (size_t)(16 + l16) * 72;

    // staging coordinates within this half's 256 threads
    const int tid256 = tid & 255;
    const int srow0 = tid256 >> 3, sch = (tid256 & 7) << 3;
    const int srow1 = srow0 + 32;

    f32x4 of[2][4] = {};
    float lsum0 = 0.f, lsum1 = 0.f;

    // ---- pipeline registers
    u32x4 kreg[2];
    f32x4 mreg[4][2];

    auto issue_k = [&](int s0) {
        kreg[0] = *(const u32x4*)(kg + (size_t)(s0 + srow0) * 64 + sch);
        kreg[1] = *(const u32x4*)(kg + (size_t)(s0 + srow1) * 64 + sch);
    };
    auto issue_mask = [&](int s0) {
        #pragma unroll
        for (int sm = 0; sm < 4; ++sm) {
            int sbase = s0 + (sm << 4) + (q << 2);
            int sclamp = sbase > 2121 ? 2121 : sbase;     // clamped lanes are
            f32x4a m0 = *(const f32x4a*)(mrow0 + sclamp); // masked to -1e30
            f32x4a m1 = *(const f32x4a*)(mrow1 + sclamp); // in the tail tile
            mreg[sm][0] = f32x4{m0.x, m0.y, m0.z, m0.w};
            mreg[sm][1] = f32x4{m1.x, m1.y, m1.z, m1.w};
        }
    };

    issue_k(sb);
    issue_mask(sb);

    for (int ks = 0; ks < 17; ++ks) {
        const int s0 = sb + (ks << 6);
        unsigned short* const kb = k_lds[h2][ks & 1];
        // ---- staging: registers -> LDS buf[ks&1] (vmcnt wait auto-inserted)
        *(u32x4*)(kb + srow0 * 72 + sch) = kreg[0];
        *(u32x4*)(kb + srow1 * 72 + sch) = kreg[1];
        __syncthreads();                       // single barrier per tile
        // ---- prefetch next tile's K into registers (latency overlapped)
        if (ks < 16) issue_k(s0 + 64);

        const bool tail = (s0 + 64 > 2125);    // only h2=1, ks=16
        // ---- QK^T + mask + softmax; K A-frags shared by both t-halves
        #pragma unroll
        for (int sm = 0; sm < 4; ++sm) {
            const unsigned short* kp = kb + (size_t)((sm << 4) + l16) * 72 + (q << 3);
            bf16x8 ak0 = *(const bf16x8*)(kp);
            bf16x8 ak1 = *(const bf16x8*)(kp + 32);
            int sbase = s0 + (sm << 4) + (q << 2);
            #pragma unroll
            for (int h = 0; h < 2; ++h) {
                f32x4 acc = {};
                acc = __builtin_amdgcn_mfma_f32_16x16x32_bf16(ak0, qf[h][0], acc, 0, 0, 0);
                acc = __builtin_amdgcn_mfma_f32_16x16x32_bf16(ak1, qf[h][1], acc, 0, 0, 0);
                acc += mreg[sm][h];
                if (tail) {
                    #pragma unroll
                    for (int j = 0; j < 4; ++j)
                        if (sbase + j >= 2125) acc[j] = -1e30f;
                }
                float p0 = __builtin_amdgcn_exp2f(__builtin_fmaf(acc[0], L2E, NEGM));
                float p1 = __builtin_amdgcn_exp2f(__builtin_fmaf(acc[1], L2E, NEGM));
                float p2 = __builtin_amdgcn_exp2f(__builtin_fmaf(acc[2], L2E, NEGM));
                float p3 = __builtin_amdgcn_exp2f(__builtin_fmaf(acc[3], L2E, NEGM));
                if (h) lsum1 += (p0 + p1) + (p2 + p3);
                else   lsum0 += (p0 + p1) + (p2 + p3);
                u32x2 pk; pk.x = pack_bf16(p0, p1); pk.y = pack_bf16(p2, p3);
                *(u32x2*)((h ? pw1 : pw0) + (sm << 4) + (q << 2)) = pk;
            }
        }
        // ---- prefetch next tile's mask (consumed next iteration)
        if (ks < 16) issue_mask(s0 + 64);

        // ---- PV: O^T += V · P^T; V A-frags direct from global (L2-resident),
        //      shared by both t-halves
        bf16x8 bp00 = *(const bf16x8*)(pw0 + (q << 3));
        bf16x8 bp01 = *(const bf16x8*)(pw0 + (q << 3) + 32);
        bf16x8 bp10 = *(const bf16x8*)(pw1 + (q << 3));
        bf16x8 bp11 = *(const bf16x8*)(pw1 + (q << 3) + 32);
        #pragma unroll
        for (int cm = 0; cm < 4; ++cm) {
            const unsigned short* vp = vg + (size_t)((cm << 4) + l16) * 2176 + s0 + (q << 3);
            bf16x8 av0 = *(const bf16x8*)(vp);
            bf16x8 av1 = *(const bf16x8*)(vp + 32);
            of[0][cm] = __builtin_amdgcn_mfma_f32_16x16x32_bf16(av0, bp00, of[0][cm], 0, 0, 0);
            of[0][cm] = __builtin_amdgcn_mfma_f32_16x16x32_bf16(av1, bp01, of[0][cm], 0, 0, 0);
            of[1][cm] = __builtin_amdgcn_mfma_f32_16x16x32_bf16(av0, bp10, of[1][cm], 0, 0, 0);
            of[1][cm] = __builtin_amdgcn_mfma_f32_16x16x32_bf16(av1, bp11, of[1][cm], 0, 0, 0);
        }
    }

    // ---- reduce l over quads (all lanes end with full column sums)
    lsum0 += __shfl_xor(lsum0, 16, 64);
    lsum0 += __shfl_xor(lsum0, 32, 64);
    lsum1 += __shfl_xor(lsum1, 16, 64);
    lsum1 += __shfl_xor(lsum1, 32, 64);

    // ---- cross-half combine: exact (fixed softmax max). Reuse k_lds region.
    float* cof  = (float*)(&k_lds[0][0][0]);   // [128][68] f32 = 34816B
    float* csum = cof + 128 * 68;              // [128] f32
    __syncthreads();                           // all LDS reads of loop done
    if (h2) {
        #pragma unroll
        for (int h = 0; h < 2; ++h) {
            const int tl = (wv << 5) + (h << 4) + l16;
            #pragma unroll
            for (int cm = 0; cm < 4; ++cm)
                *(f32x4*)(cof + (size_t)tl * 68 + (cm << 4) + (q << 2)) = of[h][cm];
        }
        if (lane < 16) {
            csum[(wv << 5) + lane]      = lsum0;
            csum[(wv << 5) + 16 + lane] = lsum1;
        }
    }
    __syncthreads();
    if (!h2) {
        const int tl0 = (wv << 5) + l16, tl1 = tl0 + 16;
        const float inv0 = 1.0f / (lsum0 + csum[tl0]);
        const float inv1 = 1.0f / (lsum1 + csum[tl1]);
        #pragma unroll
        for (int cm = 0; cm < 4; ++cm) {
            f32x4 p0 = *(const f32x4*)(cof + (size_t)tl0 * 68 + (cm << 4) + (q << 2));
            f32x4 p1 = *(const f32x4*)(cof + (size_t)tl1 * 68 + (cm << 4) + (q << 2));
            #pragma unroll
            for (int j = 0; j < 4; ++j) {
                int c = (cm << 4) + (q << 2) + j;
                float* o = out + ((size_t)n * 64 + c) * 2048;
                o[tc0] = (of[0][cm][j] + p0[j]) * inv0;
                o[tc1] = (of[1][cm][j] + p1[j]) * inv1;
            }
        }
    }
}

// ---------------------------------------------------------------------------
extern "C" void kernel_launch(void* const* d_in, const int* in_sizes, int n_in,
                              void* d_out, int out_size, void* d_ws, size_t ws_size,
                              hipStream_t stream) {
    const float* qkv  = (const float*)d_in[0];   // [32][192][2048] fp32
    const float* ekv  = (const float*)d_in[1];   // [32][128][77]   fp32
    const float* mask = (const float*)d_in[2];   // [1][2048][2125] fp32
    float* out = (float*)d_out;                  // [32][64][2048]  fp32

    unsigned short* kws = (unsigned short*)d_ws;                   // 32*2176*64
    unsigned short* vws = kws + (size_t)32 * 2176 * 64;            // 32*64*2176
    // ws use: ~17.8 MB (unchanged)

    prep_all<<<3136, 256, 0, stream>>>(qkv, ekv, kws, vws);
    dim3 grid(16, 32);                                             // (t-tiles, heads)
    flash_attn<<<grid, 512, 0, stream>>>(qkv, kws, vws, mask, out);
}

// Round 2
// 257.960 us; speedup vs baseline: 1.0667x; 1.0667x over previous
//
#include <hip/hip_runtime.h>

// ---------------------------------------------------------------------------
// QKVAttention: out[b,c,t] = softmax_s( (q/8)·k + mask )[t,s] · v[c,s]
// N=32, CH=64, T=2048, S_enc=77, S_tot=2125 (pad 2176 = 34 tiles of 64)
// v8: v7 structure (s-split x2 in-block, V direct from global, K LDS relay)
//     with the register clamp fixed: __launch_bounds__(512, 2).
//     v7's (512,4) forced VGPR=64 -> ~130MB scratch spill traffic
//     (WRITE_SIZE 16->149MB, MfmaUtil 16->7.7%). Per-thread state needs ~100
//     VGPRs; cap 256 lets allocator land ~96-112 <= 128, keeping the
//     LDS-limited 2 blocks/CU = 16 waves/CU occupancy WITHOUT spills.
// ---------------------------------------------------------------------------

typedef __attribute__((ext_vector_type(8))) __bf16 bf16x8;
typedef __attribute__((ext_vector_type(8))) unsigned short u16x8;
typedef __attribute__((ext_vector_type(4))) float f32x4;
typedef float f32x4a __attribute__((ext_vector_type(4))) __attribute__((aligned(4)));
typedef __attribute__((ext_vector_type(4))) unsigned u32x4;
typedef __attribute__((ext_vector_type(2))) unsigned u32x2;

#define L2E  1.44269504089f
#define NEGM (-23.0830936f)   /* -16 * log2(e): fixed softmax max */

static __device__ __forceinline__ unsigned short f2bf(float f) {
    unsigned u = __builtin_bit_cast(unsigned, f);
    u += 0x7fffu + ((u >> 16) & 1u);   // round-to-nearest-even
    return (unsigned short)(u >> 16);
}

static __device__ __forceinline__ unsigned pack_bf16(float a, float b) {
#if __has_builtin(__builtin_amdgcn_cvt_pk_bf16_f32)
    typedef __bf16 bf16x2_t __attribute__((ext_vector_type(2)));
    bf16x2_t r = __builtin_amdgcn_cvt_pk_bf16_f32(a, b);
    unsigned u; __builtin_memcpy(&u, &r, 4);
    return u;
#else
    unsigned ua = __builtin_bit_cast(unsigned, a);
    unsigned ub = __builtin_bit_cast(unsigned, b);
    ua += 0x7fffu + ((ua >> 16) & 1u);
    ub += 0x7fffu + ((ub >> 16) & 1u);
    return __builtin_amdgcn_perm(ub, ua, 0x07060302u);
#endif
}

// ---------------------------------------------------------------------------
// Merged prep (unchanged, verified). blocks: [0,1024) K-self transpose,
// [1024,1088) K-enc transpose, [1088,3136) V rows.
// K_ws[n][s][c] (2176 rows; pad rows poison — masked in flash),
// V_ws[n][c][s] (zero-padded to 2176).
// ---------------------------------------------------------------------------
__global__ __launch_bounds__(256) void prep_all(const float* __restrict__ qkv,
                                                const float* __restrict__ ekv,
                                                unsigned short* __restrict__ kws,
                                                unsigned short* __restrict__ vws) {
    int b = blockIdx.x;
    int tid = threadIdx.x;

    if (b >= 1088) {                    // ---- V mode: one (n,c) row
        int bb = b - 1088;
        int n = bb >> 6, c = bb & 63;
        const float* v  = qkv + (size_t)n * 192 * 2048 + (size_t)(128 + c) * 2048;
        const float* ev = ekv + (size_t)n * 128 * 77 + (size_t)(64 + c) * 77;
        unsigned short* dst = vws + ((size_t)n * 64 + c) * 2176;
        for (int u = tid; u < 544; u += 256) {
            int s = u << 2;
            float f[4];
            if (u >= 20 && u <= 530) {           // pure self-V region
                f32x4a x = *(const f32x4a*)(v + s - 77);
                f[0] = x.x; f[1] = x.y; f[2] = x.z; f[3] = x.w;
            } else {
                #pragma unroll
                for (int k = 0; k < 4; ++k) {
                    int sk = s + k;
                    f[k] = (sk < 77) ? ev[sk] : ((sk < 2125) ? v[sk - 77] : 0.f);
                }
            }
            u32x2 pk; pk.x = pack_bf16(f[0], f[1]); pk.y = pack_bf16(f[2], f[3]);
            *(u32x2*)(dst + s) = pk;
        }
        return;
    }

    // ---- K transpose modes (self / enc): [c][t] -> [t][c]
    __shared__ float tile[64][65];
    int mode, n, t0;
    if (b < 1024) { mode = 1; n = b >> 5;          t0 = (b & 31) << 6; }
    else          { mode = 2; n = (b - 1024) >> 1; t0 = ((b - 1024) & 1) << 6; }

    const float* src;
    size_t srow;
    int tmax = 64;
    if (mode == 1) { src = qkv + (size_t)n * 192 * 2048 + (size_t)64 * 2048 + t0; srow = 2048; }
    else           { src = ekv + (size_t)n * 128 * 77 + t0; srow = 77;
                     tmax = 77 - t0; if (tmax > 64) tmax = 64; }

    #pragma unroll
    for (int i = 0; i < 4; ++i) {
        int idx = tid + (i << 8);
        int c  = idx >> 4;
        int t4 = (idx & 15) << 2;
        const float* p = src + (size_t)c * srow + t4;
        float v0, v1, v2, v3;
        if (mode == 1) {
            f32x4 v = *(const f32x4*)p;
            v0 = v.x; v1 = v.y; v2 = v.z; v3 = v.w;
        } else {
            v0 = (t4 + 0 < tmax) ? p[0] : 0.f;
            v1 = (t4 + 1 < tmax) ? p[1] : 0.f;
            v2 = (t4 + 2 < tmax) ? p[2] : 0.f;
            v3 = (t4 + 3 < tmax) ? p[3] : 0.f;
        }
        tile[t4 + 0][c] = v0;
        tile[t4 + 1][c] = v1;
        tile[t4 + 2][c] = v2;
        tile[t4 + 3][c] = v3;
    }
    __syncthreads();
    #pragma unroll
    for (int i = 0; i < 4; ++i) {       // 1024 b64 units (row, 4c)
        int idx = tid + (i << 8);
        int row = idx >> 4;
        int c4  = (idx & 15) << 2;
        if (mode == 2 && row >= tmax) continue;
        u32x2 pk;
        pk.x = pack_bf16(tile[row][c4 + 0], tile[row][c4 + 1]);
        pk.y = pack_bf16(tile[row][c4 + 2], tile[row][c4 + 3]);
        unsigned short* dst;
        if (mode == 1) dst = kws + ((size_t)n * 2176 + 77 + t0 + row) * 64;
        else           dst = kws + ((size_t)n * 2176 + t0 + row) * 64;
        *(u32x2*)(dst + c4) = pk;
    }
}

// ---------------------------------------------------------------------------
// Flash attention v8. 512 threads = 8 waves: wave = 4*h2 + wv.
//   h2 = s-half (0: tiles 0..16, 1: tiles 17..33), wv = t-position.
//   t-tile = 128 (4 wv x 32 t-cols, two 16-col halves). 17 s-tiles per wave.
// S^T = K·Q^T, O^T = V·P^T, mfma_f32_16x16x32_bf16.
// K: register-relay + per-half double-buffered LDS, ONE barrier per tile.
// V: direct global fragment reads (vws is L2/L3-resident; 64B-contig rows).
// P: per-wave LDS scratch (no barrier).
// Fixed softmax max => cross-half (O, lsum) combine is exact addition,
// done once in LDS at the end (reusing the K region).
// Hazard (as v6): reads of k buf[x] (iter k) precede barrier(k+1); writes of
// buf[x] (iter k+2) follow it. LDS rows padded +8 shorts (144B stride).
// Layouts (verified R1/v3/v4/v5): A[m=lane&15][k=quad*8+j],
// B[k=quad*8+j][n=lane&15], C/D: col=lane&15, row=quad*4+reg.
// ---------------------------------------------------------------------------
__global__ __launch_bounds__(512, 2) void flash_attn(
        const float* __restrict__ qkv,
        const unsigned short* __restrict__ kws,
        const unsigned short* __restrict__ vws,
        const float* __restrict__ mask,
        float* __restrict__ out) {
    __shared__ alignas(16) unsigned short k_lds[2][2][64 * 72]; // [half][buf] 36864B
    __shared__ alignas(16) unsigned short p_lds[8][32 * 72];    // 36864B per-wave P[t][s]

    const int n    = blockIdx.y;
    const int t0   = blockIdx.x << 7;
    const int tid  = threadIdx.x;
    const int wave = tid >> 6;
    const int h2   = wave >> 2;                // s-half
    const int wv   = wave & 3;                 // t-position
    const int lane = tid & 63;
    const int q    = lane >> 4;
    const int l16  = lane & 15;
    const int tc0  = t0 + (wv << 5) + l16;     // half 0 column
    const int tc1  = tc0 + 16;                 // half 1 column
    const int sb   = h2 * 1088;                // 17 tiles * 64

    // ---- Q B-fragments for both halves, direct from fp32 qkv[n][c][t]
    bf16x8 qf[2][2];
    #pragma unroll
    for (int h = 0; h < 2; ++h) {
        const float* qsrc = qkv + (size_t)n * 192 * 2048 + (h ? tc1 : tc0);
        u16x8 a0, a1;
        #pragma unroll
        for (int j = 0; j < 8; ++j) {
            a0[j] = f2bf(qsrc[(size_t)((q << 3) + j) * 2048] * 0.125f);
            a1[j] = f2bf(qsrc[(size_t)(32 + (q << 3) + j) * 2048] * 0.125f);
        }
        qf[h][0] = __builtin_bit_cast(bf16x8, a0);
        qf[h][1] = __builtin_bit_cast(bf16x8, a1);
    }

    const unsigned short* kg = kws + (size_t)n * 2176 * 64;
    const unsigned short* vg = vws + (size_t)n * 64 * 2176;
    const float* mrow0 = mask + (size_t)tc0 * 2125;
    const float* mrow1 = mask + (size_t)tc1 * 2125;
    unsigned short* const pw0 = p_lds[wave] + (size_t)l16 * 72;
    unsigned short* const pw1 = p_lds[wave] + (size_t)(16 + l16) * 72;

    // staging coordinates within this half's 256 threads
    const int tid256 = tid & 255;
    const int srow0 = tid256 >> 3, sch = (tid256 & 7) << 3;
    const int srow1 = srow0 + 32;

    f32x4 of[2][4] = {};
    float lsum0 = 0.f, lsum1 = 0.f;

    // ---- pipeline registers
    u32x4 kreg[2];
    f32x4 mreg[4][2];

    auto issue_k = [&](int s0) {
        kreg[0] = *(const u32x4*)(kg + (size_t)(s0 + srow0) * 64 + sch);
        kreg[1] = *(const u32x4*)(kg + (size_t)(s0 + srow1) * 64 + sch);
    };
    auto issue_mask = [&](int s0) {
        #pragma unroll
        for (int sm = 0; sm < 4; ++sm) {
            int sbase = s0 + (sm << 4) + (q << 2);
            int sclamp = sbase > 2121 ? 2121 : sbase;     // clamped lanes are
            f32x4a m0 = *(const f32x4a*)(mrow0 + sclamp); // masked to -1e30
            f32x4a m1 = *(const f32x4a*)(mrow1 + sclamp); // in the tail tile
            mreg[sm][0] = f32x4{m0.x, m0.y, m0.z, m0.w};
            mreg[sm][1] = f32x4{m1.x, m1.y, m1.z, m1.w};
        }
    };

    issue_k(sb);
    issue_mask(sb);

    for (int ks = 0; ks < 17; ++ks) {
        const int s0 = sb + (ks << 6);
        unsigned short* const kb = k_lds[h2][ks & 1];
        // ---- staging: registers -> LDS buf[ks&1] (vmcnt wait auto-inserted)
        *(u32x4*)(kb + srow0 * 72 + sch) = kreg[0];
        *(u32x4*)(kb + srow1 * 72 + sch) = kreg[1];
        __syncthreads();                       // single barrier per tile
        // ---- prefetch next tile's K into registers (latency overlapped)
        if (ks < 16) issue_k(s0 + 64);

        const bool tail = (s0 + 64 > 2125);    // only h2=1, ks=16
        // ---- QK^T + mask + softmax; K A-frags shared by both t-halves
        #pragma unroll
        for (int sm = 0; sm < 4; ++sm) {
            const unsigned short* kp = kb + (size_t)((sm << 4) + l16) * 72 + (q << 3);
            bf16x8 ak0 = *(const bf16x8*)(kp);
            bf16x8 ak1 = *(const bf16x8*)(kp + 32);
            int sbase = s0 + (sm << 4) + (q << 2);
            #pragma unroll
            for (int h = 0; h < 2; ++h) {
                f32x4 acc = {};
                acc = __builtin_amdgcn_mfma_f32_16x16x32_bf16(ak0, qf[h][0], acc, 0, 0, 0);
                acc = __builtin_amdgcn_mfma_f32_16x16x32_bf16(ak1, qf[h][1], acc, 0, 0, 0);
                acc += mreg[sm][h];
                if (tail) {
                    #pragma unroll
                    for (int j = 0; j < 4; ++j)
                        if (sbase + j >= 2125) acc[j] = -1e30f;
                }
                float p0 = __builtin_amdgcn_exp2f(__builtin_fmaf(acc[0], L2E, NEGM));
                float p1 = __builtin_amdgcn_exp2f(__builtin_fmaf(acc[1], L2E, NEGM));
                float p2 = __builtin_amdgcn_exp2f(__builtin_fmaf(acc[2], L2E, NEGM));
                float p3 = __builtin_amdgcn_exp2f(__builtin_fmaf(acc[3], L2E, NEGM));
                if (h) lsum1 += (p0 + p1) + (p2 + p3);
                else   lsum0 += (p0 + p1) + (p2 + p3);
                u32x2 pk; pk.x = pack_bf16(p0, p1); pk.y = pack_bf16(p2, p3);
                *(u32x2*)((h ? pw1 : pw0) + (sm << 4) + (q << 2)) = pk;
            }
        }
        // ---- prefetch next tile's mask (consumed next iteration)
        if (ks < 16) issue_mask(s0 + 64);

        // ---- PV: O^T += V · P^T; V A-frags direct from global (L2-resident),
        //      shared by both t-halves
        bf16x8 bp00 = *(const bf16x8*)(pw0 + (q << 3));
        bf16x8 bp01 = *(const bf16x8*)(pw0 + (q << 3) + 32);
        bf16x8 bp10 = *(const bf16x8*)(pw1 + (q << 3));
        bf16x8 bp11 = *(const bf16x8*)(pw1 + (q << 3) + 32);
        #pragma unroll
        for (int cm = 0; cm < 4; ++cm) {
            const unsigned short* vp = vg + (size_t)((cm << 4) + l16) * 2176 + s0 + (q << 3);
            bf16x8 av0 = *(const bf16x8*)(vp);
            bf16x8 av1 = *(const bf16x8*)(vp + 32);
            of[0][cm] = __builtin_amdgcn_mfma_f32_16x16x32_bf16(av0, bp00, of[0][cm], 0, 0, 0);
            of[0][cm] = __builtin_amdgcn_mfma_f32_16x16x32_bf16(av1, bp01, of[0][cm], 0, 0, 0);
            of[1][cm] = __builtin_amdgcn_mfma_f32_16x16x32_bf16(av0, bp10, of[1][cm], 0, 0, 0);
            of[1][cm] = __builtin_amdgcn_mfma_f32_16x16x32_bf16(av1, bp11, of[1][cm], 0, 0, 0);
        }
    }

    // ---- reduce l over quads (all lanes end with full column sums)
    lsum0 += __shfl_xor(lsum0, 16, 64);
    lsum0 += __shfl_xor(lsum0, 32, 64);
    lsum1 += __shfl_xor(lsum1, 16, 64);
    lsum1 += __shfl_xor(lsum1, 32, 64);

    // ---- cross-half combine: exact (fixed softmax max). Reuse k_lds region.
    float* cof  = (float*)(&k_lds[0][0][0]);   // [128][68] f32 = 34816B
    float* csum = cof + 128 * 68;              // [128] f32
    __syncthreads();                           // all LDS reads of loop done
    if (h2) {
        #pragma unroll
        for (int h = 0; h < 2; ++h) {
            const int tl = (wv << 5) + (h << 4) + l16;
            #pragma unroll
            for (int cm = 0; cm < 4; ++cm)
                *(f32x4*)(cof + (size_t)tl * 68 + (cm << 4) + (q << 2)) = of[h][cm];
        }
        if (lane < 16) {
            csum[(wv << 5) + lane]      = lsum0;
            csum[(wv << 5) + 16 + lane] = lsum1;
        }
    }
    __syncthreads();
    if (!h2) {
        const int tl0 = (wv << 5) + l16, tl1 = tl0 + 16;
        const float inv0 = 1.0f / (lsum0 + csum[tl0]);
        const float inv1 = 1.0f / (lsum1 + csum[tl1]);
        #pragma unroll
        for (int cm = 0; cm < 4; ++cm) {
            f32x4 p0 = *(const f32x4*)(cof + (size_t)tl0 * 68 + (cm << 4) + (q << 2));
            f32x4 p1 = *(const f32x4*)(cof + (size_t)tl1 * 68 + (cm << 4) + (q << 2));
            #pragma unroll
            for (int j = 0; j < 4; ++j) {
                int c = (cm << 4) + (q << 2) + j;
                float* o = out + ((size_t)n * 64 + c) * 2048;
                o[tc0] = (of[0][cm][j] + p0[j]) * inv0;
                o[tc1] = (of[1][cm][j] + p1[j]) * inv1;
            }
        }
    }
}

// ---------------------------------------------------------------------------
extern "C" void kernel_launch(void* const* d_in, const int* in_sizes, int n_in,
                              void* d_out, int out_size, void* d_ws, size_t ws_size,
                              hipStream_t stream) {
    const float* qkv  = (const float*)d_in[0];   // [32][192][2048] fp32
    const float* ekv  = (const float*)d_in[1];   // [32][128][77]   fp32
    const float* mask = (const float*)d_in[2];   // [1][2048][2125] fp32
    float* out = (float*)d_out;                  // [32][64][2048]  fp32

    unsigned short* kws = (unsigned short*)d_ws;                   // 32*2176*64
    unsigned short* vws = kws + (size_t)32 * 2176 * 64;            // 32*64*2176
    // ws use: ~17.8 MB (unchanged)

    prep_all<<<3136, 256, 0, stream>>>(qkv, ekv, kws, vws);
    dim3 grid(16, 32);                                             // (t-tiles, heads)
    flash_attn<<<grid, 512, 0, stream>>>(qkv, kws, vws, mask, out);
}

// Round 3
// 163.003 us; speedup vs baseline: 1.6881x; 1.5826x over previous
//
#include <hip/hip_runtime.h>

// ---------------------------------------------------------------------------
// QKVAttention: out[b,c,t] = softmax_s( (q/8)·k + mask )[t,s] · v[c,s]
// N=32, CH=64, T=2048, S_enc=77, S_tot=2125 (pad 2176 = 34 tiles of 64)
// v9: v6 base (verified 90us flash) + pipeline restructure:
//       iter k: stage(k+1); barrier; QK-MFMA(k+1)->regs; PV(k); softmax(k+1).
//     Breaks the serial [QK->exp->Pwrite->Pread->PV] chain: P round-trip and
//     exp now lead their consumer by a full phase; QK(k+1) and PV(k) are two
//     independent MFMA clusters. V triple-buffered (PV reads shifted one
//     barrier later), K double, P single (write-after-read, same wave).
//     LDS 64512B -> still 2 blocks/CU (2x64512=126KB).
//     + mask all-zero fast path: prep scans mask -> flag (kws pad row 2175,
//     memset-zeroed); flash skips mask loads/adds when zero (exact; fallback
//     path = v6 behavior).
// v8 lesson: 2x73728 LDS does NOT co-schedule (~128KB effective pool) and
//     V-from-global at MFMA-use = L3 latency on critical chain (2x slower).
// ---------------------------------------------------------------------------

typedef __attribute__((ext_vector_type(8))) __bf16 bf16x8;
typedef __attribute__((ext_vector_type(8))) unsigned short u16x8;
typedef __attribute__((ext_vector_type(4))) float f32x4;
typedef float f32x4a __attribute__((ext_vector_type(4))) __attribute__((aligned(4)));
typedef __attribute__((ext_vector_type(4))) unsigned u32x4;
typedef __attribute__((ext_vector_type(2))) unsigned u32x2;

#define L2E  1.44269504089f
#define NEGM (-23.0830936f)   /* -16 * log2(e): fixed softmax max */

static __device__ __forceinline__ unsigned short f2bf(float f) {
    unsigned u = __builtin_bit_cast(unsigned, f);
    u += 0x7fffu + ((u >> 16) & 1u);   // round-to-nearest-even
    return (unsigned short)(u >> 16);
}

static __device__ __forceinline__ unsigned pack_bf16(float a, float b) {
#if __has_builtin(__builtin_amdgcn_cvt_pk_bf16_f32)
    typedef __bf16 bf16x2_t __attribute__((ext_vector_type(2)));
    bf16x2_t r = __builtin_amdgcn_cvt_pk_bf16_f32(a, b);
    unsigned u; __builtin_memcpy(&u, &r, 4);
    return u;
#else
    unsigned ua = __builtin_bit_cast(unsigned, a);
    unsigned ub = __builtin_bit_cast(unsigned, b);
    ua += 0x7fffu + ((ua >> 16) & 1u);
    ub += 0x7fffu + ((ub >> 16) & 1u);
    return __builtin_amdgcn_perm(ub, ua, 0x07060302u);
#endif
}

// ---------------------------------------------------------------------------
// Merged prep. blocks: [0,1024) K-self transpose, [1024,1088) K-enc
// transpose, [1088,3136) V rows, [3136,3648) mask all-zero scan.
// K_ws[n][s][c] (2176 rows; pad rows 2125..2175 stay poison EXCEPT row 2175
// word 0 = mask-nonzero flag — staged as K but masked in flash).
// V_ws[n][c][s] (zero-padded to 2176).
// ---------------------------------------------------------------------------
__global__ __launch_bounds__(256) void prep_all(const float* __restrict__ qkv,
                                                const float* __restrict__ ekv,
                                                unsigned short* __restrict__ kws,
                                                unsigned short* __restrict__ vws,
                                                const float* __restrict__ mask) {
    int b = blockIdx.x;
    int tid = threadIdx.x;

    if (b >= 3136) {                    // ---- mask scan: OR all bits
        int bb = b - 3136;              // 0..511
        const u32x4* m4 = (const u32x4*)mask;   // 2048*2125 f32 = 1088000 x 16B
        unsigned acc = 0;
        for (int i = (bb << 8) + tid; i < 1088000; i += 131072) {
            u32x4 x = m4[i];
            acc |= x.x | x.y | x.z | x.w;
        }
        if (acc) atomicOr((unsigned*)(kws + (size_t)2175 * 64), 1u);
        return;
    }

    if (b >= 1088) {                    // ---- V mode: one (n,c) row
        int bb = b - 1088;
        int n = bb >> 6, c = bb & 63;
        const float* v  = qkv + (size_t)n * 192 * 2048 + (size_t)(128 + c) * 2048;
        const float* ev = ekv + (size_t)n * 128 * 77 + (size_t)(64 + c) * 77;
        unsigned short* dst = vws + ((size_t)n * 64 + c) * 2176;
        for (int u = tid; u < 544; u += 256) {
            int s = u << 2;
            float f[4];
            if (u >= 20 && u <= 530) {           // pure self-V region
                f32x4a x = *(const f32x4a*)(v + s - 77);
                f[0] = x.x; f[1] = x.y; f[2] = x.z; f[3] = x.w;
            } else {
                #pragma unroll
                for (int k = 0; k < 4; ++k) {
                    int sk = s + k;
                    f[k] = (sk < 77) ? ev[sk] : ((sk < 2125) ? v[sk - 77] : 0.f);
                }
            }
            u32x2 pk; pk.x = pack_bf16(f[0], f[1]); pk.y = pack_bf16(f[2], f[3]);
            *(u32x2*)(dst + s) = pk;
        }
        return;
    }

    // ---- K transpose modes (self / enc): [c][t] -> [t][c]
    __shared__ float tile[64][65];
    int mode, n, t0;
    if (b < 1024) { mode = 1; n = b >> 5;          t0 = (b & 31) << 6; }
    else          { mode = 2; n = (b - 1024) >> 1; t0 = ((b - 1024) & 1) << 6; }

    const float* src;
    size_t srow;
    int tmax = 64;
    if (mode == 1) { src = qkv + (size_t)n * 192 * 2048 + (size_t)64 * 2048 + t0; srow = 2048; }
    else           { src = ekv + (size_t)n * 128 * 77 + t0; srow = 77;
                     tmax = 77 - t0; if (tmax > 64) tmax = 64; }

    #pragma unroll
    for (int i = 0; i < 4; ++i) {
        int idx = tid + (i << 8);
        int c  = idx >> 4;
        int t4 = (idx & 15) << 2;
        const float* p = src + (size_t)c * srow + t4;
        float v0, v1, v2, v3;
        if (mode == 1) {
            f32x4 v = *(const f32x4*)p;
            v0 = v.x; v1 = v.y; v2 = v.z; v3 = v.w;
        } else {
            v0 = (t4 + 0 < tmax) ? p[0] : 0.f;
            v1 = (t4 + 1 < tmax) ? p[1] : 0.f;
            v2 = (t4 + 2 < tmax) ? p[2] : 0.f;
            v3 = (t4 + 3 < tmax) ? p[3] : 0.f;
        }
        tile[t4 + 0][c] = v0;
        tile[t4 + 1][c] = v1;
        tile[t4 + 2][c] = v2;
        tile[t4 + 3][c] = v3;
    }
    __syncthreads();
    #pragma unroll
    for (int i = 0; i < 4; ++i) {       // 1024 b64 units (row, 4c)
        int idx = tid + (i << 8);
        int row = idx >> 4;
        int c4  = (idx & 15) << 2;
        if (mode == 2 && row >= tmax) continue;
        u32x2 pk;
        pk.x = pack_bf16(tile[row][c4 + 0], tile[row][c4 + 1]);
        pk.y = pack_bf16(tile[row][c4 + 2], tile[row][c4 + 3]);
        unsigned short* dst;
        if (mode == 1) dst = kws + ((size_t)n * 2176 + 77 + t0 + row) * 64;
        else           dst = kws + ((size_t)n * 2176 + t0 + row) * 64;
        *(u32x2*)(dst + c4) = pk;
    }
}

// ---------------------------------------------------------------------------
// Flash attention v9. t-tile = 128 (4 waves x 32 t-cols, two 16-col halves);
// 34 s-tiles of 64. S^T = K·Q^T, O^T = V·P^T, mfma_f32_16x16x32_bf16.
// Pipeline (one barrier per tile):
//   prologue: stage(0); B; QKM(0); SMAX(0)
//   iter k=0..32: stage(k+1); B_k; issue_kv(k+2); QKM(k+1)->sacc; PV(k);
//                 SMAX(k+1)->p_lds; issue_mask(k+2)
//   epilogue: PV(33); normalize; store.
// Hazards (verified by barrier counting):
//   K[2]: write stage(k+1) preB_k / read QKM(k+1) postB_k (RAW over B_k);
//         prior read QKM(k-1) separated by B_{k-1} (WAR). OK double-buffered.
//   V[3]: read PV(k) is one barrier later than v6 -> triple buffer.
//         RAW: stage(k+1) preB_k -> PV(k+1) postB_{k+1}. WAR: PV(k-2)
//         (preB_{k-1}) -> stage(k+1) (postB_{k-1}). OK.
//   P:    per-wave; PV(k) read precedes SMAX(k+1) overwrite in program order.
// Layouts (verified R1/v3/v4/v5): A[m=lane&15][k=quad*8+j],
// B[k=quad*8+j][n=lane&15], C/D: col=lane&15, row=quad*4+reg.
// Mask fast path: flag word (kws row 2175) == 0 -> skip mask loads/adds.
// ---------------------------------------------------------------------------
__global__ __launch_bounds__(256, 2) void flash_attn(
        const float* __restrict__ qkv,
        const unsigned short* __restrict__ kws,
        const unsigned short* __restrict__ vws,
        const float* __restrict__ mask,
        float* __restrict__ out) {
    __shared__ alignas(16) unsigned short k_lds[2][64 * 72]; // 18432B [s][c]
    __shared__ alignas(16) unsigned short v_lds[3][64 * 72]; // 27648B [c][s]
    __shared__ alignas(16) unsigned short p_lds[4][32 * 72]; // 18432B per-wave P[t][s]

    const int n    = blockIdx.y;
    const int t0   = blockIdx.x << 7;
    const int tid  = threadIdx.x;
    const int wave = tid >> 6;
    const int lane = tid & 63;
    const int q    = lane >> 4;
    const int l16  = lane & 15;
    const int tc0  = t0 + (wave << 5) + l16;   // half 0 column
    const int tc1  = tc0 + 16;                 // half 1 column

    // ---- mask-nonzero flag (uniform)
    const bool domask =
        __builtin_amdgcn_readfirstlane(*(const unsigned*)(kws + (size_t)2175 * 64)) != 0u;

    // ---- Q B-fragments for both halves, direct from fp32 qkv[n][c][t]
    bf16x8 qf[2][2];
    #pragma unroll
    for (int h = 0; h < 2; ++h) {
        const float* qsrc = qkv + (size_t)n * 192 * 2048 + (h ? tc1 : tc0);
        u16x8 a0, a1;
        #pragma unroll
        for (int j = 0; j < 8; ++j) {
            a0[j] = f2bf(qsrc[(size_t)((q << 3) + j) * 2048] * 0.125f);
            a1[j] = f2bf(qsrc[(size_t)(32 + (q << 3) + j) * 2048] * 0.125f);
        }
        qf[h][0] = __builtin_bit_cast(bf16x8, a0);
        qf[h][1] = __builtin_bit_cast(bf16x8, a1);
    }

    const unsigned short* kg = kws + (size_t)n * 2176 * 64;
    const unsigned short* vg = vws + (size_t)n * 64 * 2176;
    const float* mrow0 = mask + (size_t)tc0 * 2125;
    const float* mrow1 = mask + (size_t)tc1 * 2125;
    unsigned short* const pw0 = p_lds[wave] + (size_t)l16 * 72;
    unsigned short* const pw1 = p_lds[wave] + (size_t)(16 + l16) * 72;

    // staging coordinates (fixed per thread)
    const int srow0 = tid >> 3,        sch = (tid & 7) << 3;   // chunk 0
    const int srow1 = srow0 + 32;                              // chunk 1

    f32x4 of[2][4] = {};
    f32x4 sacc[4][2];              // held QK results across the PV phase
    float lsum0 = 0.f, lsum1 = 0.f;

    // ---- pipeline registers
    u32x4 kreg[2], vreg[2];
    f32x4 mreg[4][2];

    auto issue_kv = [&](int s0) {
        kreg[0] = *(const u32x4*)(kg + (size_t)(s0 + srow0) * 64 + sch);
        vreg[0] = *(const u32x4*)(vg + (size_t)srow0 * 2176 + s0 + sch);
        kreg[1] = *(const u32x4*)(kg + (size_t)(s0 + srow1) * 64 + sch);
        vreg[1] = *(const u32x4*)(vg + (size_t)srow1 * 2176 + s0 + sch);
    };
    auto issue_mask = [&](int s0) {
        #pragma unroll
        for (int sm = 0; sm < 4; ++sm) {
            int sbase = s0 + (sm << 4) + (q << 2);
            int sclamp = sbase > 2121 ? 2121 : sbase;     // clamped lanes are
            f32x4a m0 = *(const f32x4a*)(mrow0 + sclamp); // masked to -1e30
            f32x4a m1 = *(const f32x4a*)(mrow1 + sclamp); // in the tail tile
            mreg[sm][0] = f32x4{m0.x, m0.y, m0.z, m0.w};
            mreg[sm][1] = f32x4{m1.x, m1.y, m1.z, m1.w};
        }
    };
    auto stage = [&](unsigned short* kb, unsigned short* vb) {
        *(u32x4*)(kb + srow0 * 72 + sch) = kreg[0];
        *(u32x4*)(vb + srow0 * 72 + sch) = vreg[0];
        *(u32x4*)(kb + srow1 * 72 + sch) = kreg[1];
        *(u32x4*)(vb + srow1 * 72 + sch) = vreg[1];
    };
    auto qkm = [&](const unsigned short* kb) {   // QK MFMAs only -> sacc
        #pragma unroll
        for (int sm = 0; sm < 4; ++sm) {
            const unsigned short* kp = kb + (size_t)((sm << 4) + l16) * 72 + (q << 3);
            bf16x8 ak0 = *(const bf16x8*)(kp);
            bf16x8 ak1 = *(const bf16x8*)(kp + 32);
            #pragma unroll
            for (int h = 0; h < 2; ++h) {
                f32x4 a = {};
                a = __builtin_amdgcn_mfma_f32_16x16x32_bf16(ak0, qf[h][0], a, 0, 0, 0);
                a = __builtin_amdgcn_mfma_f32_16x16x32_bf16(ak1, qf[h][1], a, 0, 0, 0);
                sacc[sm][h] = a;
            }
        }
    };
    auto smax = [&](int s0) {      // mask + softmax + P-write (consumes sacc)
        const bool tail = (s0 + 64 > 2125);
        #pragma unroll
        for (int sm = 0; sm < 4; ++sm) {
            int sbase = s0 + (sm << 4) + (q << 2);
            #pragma unroll
            for (int h = 0; h < 2; ++h) {
                f32x4 a = sacc[sm][h];
                if (domask) a += mreg[sm][h];
                if (tail) {
                    #pragma unroll
                    for (int j = 0; j < 4; ++j)
                        if (sbase + j >= 2125) a[j] = -1e30f;
                }
                float p0 = __builtin_amdgcn_exp2f(__builtin_fmaf(a[0], L2E, NEGM));
                float p1 = __builtin_amdgcn_exp2f(__builtin_fmaf(a[1], L2E, NEGM));
                float p2 = __builtin_amdgcn_exp2f(__builtin_fmaf(a[2], L2E, NEGM));
                float p3 = __builtin_amdgcn_exp2f(__builtin_fmaf(a[3], L2E, NEGM));
                if (h) lsum1 += (p0 + p1) + (p2 + p3);
                else   lsum0 += (p0 + p1) + (p2 + p3);
                u32x2 pk; pk.x = pack_bf16(p0, p1); pk.y = pack_bf16(p2, p3);
                *(u32x2*)((h ? pw1 : pw0) + (sm << 4) + (q << 2)) = pk;
            }
        }
    };
    auto pv = [&](const unsigned short* vb) {    // O^T += V · P^T
        bf16x8 bp00 = *(const bf16x8*)(pw0 + (q << 3));
        bf16x8 bp01 = *(const bf16x8*)(pw0 + (q << 3) + 32);
        bf16x8 bp10 = *(const bf16x8*)(pw1 + (q << 3));
        bf16x8 bp11 = *(const bf16x8*)(pw1 + (q << 3) + 32);
        #pragma unroll
        for (int cm = 0; cm < 4; ++cm) {
            const unsigned short* vp = vb + (size_t)((cm << 4) + l16) * 72 + (q << 3);
            bf16x8 av0 = *(const bf16x8*)(vp);
            bf16x8 av1 = *(const bf16x8*)(vp + 32);
            of[0][cm] = __builtin_amdgcn_mfma_f32_16x16x32_bf16(av0, bp00, of[0][cm], 0, 0, 0);
            of[0][cm] = __builtin_amdgcn_mfma_f32_16x16x32_bf16(av1, bp01, of[0][cm], 0, 0, 0);
            of[1][cm] = __builtin_amdgcn_mfma_f32_16x16x32_bf16(av0, bp10, of[1][cm], 0, 0, 0);
            of[1][cm] = __builtin_amdgcn_mfma_f32_16x16x32_bf16(av1, bp11, of[1][cm], 0, 0, 0);
        }
    };

    // ---- prologue: tile 0 staged + QK/softmax (no PV yet)
    issue_kv(0);
    if (domask) issue_mask(0);
    stage(k_lds[0], v_lds[0]);
    __syncthreads();
    issue_kv(64);
    qkm(k_lds[0]);
    smax(0);
    if (domask) issue_mask(64);

    // ---- main loop: iter k computes QK(k+1), PV(k), softmax(k+1)
    int vri = 0, vwi = 1;                      // v_lds ring: read k%3, write (k+1)%3
    for (int ks = 0; ks < 33; ++ks) {
        const int s1 = (ks + 1) << 6;
        stage(k_lds[(ks + 1) & 1], v_lds[vwi]);
        __syncthreads();                       // single barrier per tile
        if (ks < 32) issue_kv(s1 + 64);        // prefetch tile ks+2
        qkm(k_lds[(ks + 1) & 1]);              // QK MFMAs for tile ks+1
        pv(v_lds[vri]);                        // PV for tile ks (P from p_lds)
        smax(s1);                              // softmax tile ks+1 -> p_lds
        if (domask && ks < 32) issue_mask(s1 + 64);
        vri = (vri == 2) ? 0 : vri + 1;
        vwi = (vwi == 2) ? 0 : vwi + 1;
    }
    pv(v_lds[vri]);                            // epilogue PV for tile 33

    // ---- epilogue: reduce l over quads, normalize, store out[n][c][t]
    lsum0 += __shfl_xor(lsum0, 16, 64);
    lsum0 += __shfl_xor(lsum0, 32, 64);
    lsum1 += __shfl_xor(lsum1, 16, 64);
    lsum1 += __shfl_xor(lsum1, 32, 64);
    float inv0 = 1.0f / lsum0, inv1 = 1.0f / lsum1;
    #pragma unroll
    for (int cm = 0; cm < 4; ++cm)
        #pragma unroll
        for (int j = 0; j < 4; ++j) {
            int c = (cm << 4) + (q << 2) + j;
            float* o = out + ((size_t)n * 64 + c) * 2048;
            o[tc0] = of[0][cm][j] * inv0;
            o[tc1] = of[1][cm][j] * inv1;
        }
}

// ---------------------------------------------------------------------------
extern "C" void kernel_launch(void* const* d_in, const int* in_sizes, int n_in,
                              void* d_out, int out_size, void* d_ws, size_t ws_size,
                              hipStream_t stream) {
    const float* qkv  = (const float*)d_in[0];   // [32][192][2048] fp32
    const float* ekv  = (const float*)d_in[1];   // [32][128][77]   fp32
    const float* mask = (const float*)d_in[2];   // [1][2048][2125] fp32
    float* out = (float*)d_out;                  // [32][64][2048]  fp32

    unsigned short* kws = (unsigned short*)d_ws;                   // 32*2176*64
    unsigned short* vws = kws + (size_t)32 * 2176 * 64;            // 32*64*2176
    // ws use: ~17.8 MB (unchanged; flag lives in kws pad row 2175)

    hipMemsetAsync((char*)d_ws + (size_t)2175 * 64 * 2, 0, 4, stream);
    prep_all<<<3648, 256, 0, stream>>>(qkv, ekv, kws, vws, mask);
    dim3 grid(16, 32);                                             // (t-tiles, heads)
    flash_attn<<<grid, 256, 0, stream>>>(qkv, kws, vws, mask, out);
}